// Round 9
// baseline (281.394 us; speedup 1.0000x reference)
//
#include <hip/hip_runtime.h>
#include <math.h>

constexpr int B_ = 4, S_ = 1024, D_ = 512, H_ = 8, FF_ = 2048;
constexpr int DK_ = 64;
constexpr int C_ = 128;
constexpr int QKVLD = 1536;  // qkv buffer row stride (q|k|v)

typedef __bf16 bf16x8 __attribute__((ext_vector_type(8)));
typedef __bf16 bf16x4 __attribute__((ext_vector_type(4)));
typedef short short4v __attribute__((ext_vector_type(4)));
typedef float floatx4 __attribute__((ext_vector_type(4)));

// R18: direct global->LDS DMA (dwordx4). LDS dest is wave-uniform base +
// lane*16B (linear); swizzle achieved by pre-swizzling the per-lane GLOBAL
// source address (guide rule #21).
__device__ __forceinline__ void g2l16(const __bf16* g, __bf16* l) {
  __builtin_amdgcn_global_load_lds(
      (__attribute__((address_space(1))) void*)(unsigned long long)g,
      (__attribute__((address_space(3))) void*)(unsigned int)(unsigned long long)l,
      16, 0, 0);
}

// R19: XCD-aware bijective block swizzle (T1). Requires nwg%8==0.
__device__ __forceinline__ int xcd_swz(int lin, int nwg) {
  return (lin & 7) * (nwg >> 3) + (lin >> 3);
}

// ---------------------------------------------------------------------------
// bf16 MFMA GEMM, BK=64, 128x128 tile (ffn1 only now). global_load_lds
// staging, double-buffered LDS, ONE barrier per K-step.
// ---------------------------------------------------------------------------
template <bool OUTBF16, bool RELU, bool WRITEVT>
__global__ __launch_bounds__(256, 2) void mgemm(
    const __bf16* __restrict__ A, const __bf16* __restrict__ W,
    const float* __restrict__ bias, void* __restrict__ Yv,
    int M, int N, int K, int ldY, __bf16* __restrict__ VT) {
  __shared__ __bf16 As[2][128 * 64];
  __shared__ __bf16 Bs[2][128 * 64];
  const int tid = threadIdx.x;
  const int wave = tid >> 6, lane = tid & 63;
  const int nwg = gridDim.x * gridDim.y;
  const int lin = blockIdx.y * gridDim.x + blockIdx.x;
  const int swz = xcd_swz(lin, nwg);
  const int bm = (swz / gridDim.x) * 128, bn = (swz % gridDim.x) * 128;

  const int rsub = lane >> 3;
  const int gch = ((lane & 7) ^ rsub) * 8;
  const __bf16* gA = A + (size_t)(bm + wave * 32 + rsub) * K + gch;
  const __bf16* gB = W + (size_t)(bn + wave * 32 + rsub) * K + gch;

  const int mrow = lane & 15, g4 = lane >> 4;
  const int rsw = mrow & 7;
  const int wm = (wave & 1) * 64, wn = (wave >> 1) * 64;

  floatx4 acc[4][4];
#pragma unroll
  for (int mi = 0; mi < 4; mi++)
#pragma unroll
    for (int ni = 0; ni < 4; ni++) acc[mi][ni] = (floatx4){0.f, 0.f, 0.f, 0.f};

  const int nk = K >> 6;
  auto stage = [&](int buf, int kt) {
    const __bf16* ga = gA + (size_t)kt * 64;
    const __bf16* gb = gB + (size_t)kt * 64;
    __bf16* la = &As[buf][wave * 32 * 64];
    __bf16* lb = &Bs[buf][wave * 32 * 64];
#pragma unroll
    for (int i = 0; i < 4; i++) {
      g2l16(ga + (size_t)(i * 8) * K, la + i * 8 * 64);
      g2l16(gb + (size_t)(i * 8) * K, lb + i * 8 * 64);
    }
  };

  stage(0, 0);
  int cur = 0;
  for (int kk = 0; kk < nk; kk++) {
    __syncthreads();
    if (kk + 1 < nk) stage(cur ^ 1, kk + 1);
    const __bf16* Ab = As[cur];
    const __bf16* Bb = Bs[cur];
#pragma unroll
    for (int c = 0; c < 2; c++) {
      const int pc = (((c * 4 + g4) ^ rsw)) * 8;
      bf16x8 af[4], bfr[4];
#pragma unroll
      for (int mi = 0; mi < 4; mi++)
        af[mi] = *(const bf16x8*)(Ab + (wm + mi * 16 + mrow) * 64 + pc);
#pragma unroll
      for (int ni = 0; ni < 4; ni++)
        bfr[ni] = *(const bf16x8*)(Bb + (wn + ni * 16 + mrow) * 64 + pc);
#pragma unroll
      for (int mi = 0; mi < 4; mi++)
#pragma unroll
        for (int ni = 0; ni < 4; ni++)
          acc[mi][ni] = __builtin_amdgcn_mfma_f32_16x16x32_bf16(af[mi], bfr[ni], acc[mi][ni], 0, 0, 0);
    }
    cur ^= 1;
  }

  const int cc = lane & 15;
  const int r0 = (lane >> 4) * 4;
  float bv[4];
#pragma unroll
  for (int ni = 0; ni < 4; ni++) bv[ni] = bias[bn + wn + ni * 16 + cc];
#pragma unroll
  for (int mi = 0; mi < 4; mi++) {
#pragma unroll
    for (int ni = 0; ni < 4; ni++) {
      const int col = bn + wn + ni * 16 + cc;
      if (WRITEVT && col >= 1024) {
        const int h = (col - 1024) >> 6, d = (col - 1024) & 63;
        const int rowb = bm + wm + mi * 16 + r0;
        const int b = rowb >> 10, s = rowb & 1023;
        union { __bf16 hh[4]; unsigned long long u; } w;
#pragma unroll
        for (int i = 0; i < 4; i++) w.hh[i] = (__bf16)(acc[mi][ni][i] + bv[ni]);
        *(unsigned long long*)(VT + (size_t)(b * 8 + h) * 65536 + (size_t)d * 1024 + s) = w.u;
      } else {
#pragma unroll
        for (int i = 0; i < 4; i++) {
          float v = acc[mi][ni][i] + bv[ni];
          if (RELU) v = fmaxf(v, 0.f);
          const size_t row = bm + wm + mi * 16 + r0 + i;
          if (OUTBF16)
            ((__bf16*)Yv)[row * ldY + col] = (__bf16)v;
          else
            ((float*)Yv)[row * ldY + col] = v;
        }
      }
    }
  }
}

// ---------------------------------------------------------------------------
// R26: qkv GEMM reads f32 x/wq/wk/wv DIRECTLY (prepA dispatch eliminated —
// its outputs had no other consumer). Reg-staged cast (f32->bf16) into a
// single 24KB LDS buffer with the R12-proven 2-barrier schedule:
// sync -> regs->LDS -> sync -> prefetch next f32 -> MFMA. LDS image keeps
// the read-side swizzle invariant: logical chunk ch of row r at phys
// ch^(r&7). Bias read straight from bq/bk/bv (bn bands of 128 never
// straddle the 512-boundaries). Bit-identical math to prepA+bf16 path.
// 768 blocks @ LB(256,3) = exactly 3 rounds.
// ---------------------------------------------------------------------------
__global__ __launch_bounds__(256, 3) void mgemm_qkv(
    const float* __restrict__ x, const float* __restrict__ wq,
    const float* __restrict__ wk, const float* __restrict__ wv,
    const float* __restrict__ bq, const float* __restrict__ bk,
    const float* __restrict__ bv,
    __bf16* __restrict__ Y, __bf16* __restrict__ VT) {
  __shared__ __bf16 As[64 * 64];
  __shared__ __bf16 Bs[128 * 64];
  const int tid = threadIdx.x;
  const int wave = tid >> 6, lane = tid & 63;
  const int swz = xcd_swz((int)blockIdx.x, 768);
  const int bm = (swz / 12) * 64, bn = (swz % 12) * 128;

  const float* Wf;
  const float* bp;
  if (bn < 512)       { Wf = wq + (size_t)bn * 512;          bp = bq + bn; }
  else if (bn < 1024) { Wf = wk + (size_t)(bn - 512) * 512;  bp = bk + (bn - 512); }
  else                { Wf = wv + (size_t)(bn - 1024) * 512; bp = bv + (bn - 1024); }

  // A staging: lane -> row rA = lane>>2 (16 rows/wave), 16 cols at (lane&3)*16
  const int rA = lane >> 2, cA = (lane & 3) * 16;
  const float* gAf = x + (size_t)(bm + wave * 16 + rA) * 512 + cA;
  // B staging: lane -> row rB = lane>>1 (32 rows/wave), 32 cols at (lane&1)*32
  const int rB = lane >> 1, cB = (lane & 1) * 32;
  const float* gBf = Wf + (size_t)(wave * 32 + rB) * 512 + cB;

  const int mrow = lane & 15, g4 = lane >> 4;
  const int rsw = mrow & 7;

  floatx4 acc[8];
#pragma unroll
  for (int nj = 0; nj < 8; nj++) acc[nj] = (floatx4){0.f, 0.f, 0.f, 0.f};

  float4 pa[4], pb[8];
  auto ldg = [&](int kt) {
    const float* a = gAf + kt * 64;
#pragma unroll
    for (int i = 0; i < 4; i++) pa[i] = *(const float4*)(a + i * 4);
    const float* b = gBf + kt * 64;
#pragma unroll
    for (int i = 0; i < 8; i++) pb[i] = *(const float4*)(b + i * 4);
  };
  auto st = [&]() {
#pragma unroll
    for (int c2 = 0; c2 < 2; c2++) {
      union { __bf16 h[8]; bf16x8 v; } ua;
      ua.h[0] = (__bf16)pa[c2 * 2].x;     ua.h[1] = (__bf16)pa[c2 * 2].y;
      ua.h[2] = (__bf16)pa[c2 * 2].z;     ua.h[3] = (__bf16)pa[c2 * 2].w;
      ua.h[4] = (__bf16)pa[c2 * 2 + 1].x; ua.h[5] = (__bf16)pa[c2 * 2 + 1].y;
      ua.h[6] = (__bf16)pa[c2 * 2 + 1].z; ua.h[7] = (__bf16)pa[c2 * 2 + 1].w;
      const int ch = (lane & 3) * 2 + c2;
      *(bf16x8*)(&As[(wave * 16 + rA) * 64 + (ch ^ (rA & 7)) * 8]) = ua.v;
    }
#pragma unroll
    for (int c2 = 0; c2 < 4; c2++) {
      union { __bf16 h[8]; bf16x8 v; } ub;
      ub.h[0] = (__bf16)pb[c2 * 2].x;     ub.h[1] = (__bf16)pb[c2 * 2].y;
      ub.h[2] = (__bf16)pb[c2 * 2].z;     ub.h[3] = (__bf16)pb[c2 * 2].w;
      ub.h[4] = (__bf16)pb[c2 * 2 + 1].x; ub.h[5] = (__bf16)pb[c2 * 2 + 1].y;
      ub.h[6] = (__bf16)pb[c2 * 2 + 1].z; ub.h[7] = (__bf16)pb[c2 * 2 + 1].w;
      const int ch = (lane & 1) * 4 + c2;
      *(bf16x8*)(&Bs[(wave * 32 + rB) * 64 + (ch ^ (rB & 7)) * 8]) = ub.v;
    }
  };

  ldg(0);
  for (int kk = 0; kk < 8; kk++) {
    __syncthreads();   // previous compute done -> LDS reusable
    st();
    __syncthreads();   // LDS visible
    if (kk + 1 < 8) ldg(kk + 1);  // prefetch overlaps compute
#pragma unroll
    for (int c = 0; c < 2; c++) {
      const int pc = (((c * 4 + g4) ^ rsw)) * 8;
      bf16x8 af = *(const bf16x8*)(As + (wave * 16 + mrow) * 64 + pc);
#pragma unroll
      for (int nj = 0; nj < 8; nj++) {
        bf16x8 bfv = *(const bf16x8*)(Bs + (nj * 16 + mrow) * 64 + pc);
        acc[nj] = __builtin_amdgcn_mfma_f32_16x16x32_bf16(af, bfv, acc[nj], 0, 0, 0);
      }
    }
  }

  const int cc = lane & 15;
  const int r0 = (lane >> 4) * 4;
#pragma unroll
  for (int nj = 0; nj < 8; nj++) {
    const int col = bn + nj * 16 + cc;
    const float bb = bp[nj * 16 + cc];
    if (col >= 1024) {
      const int h = (col - 1024) >> 6, d = (col - 1024) & 63;
      const int rowb = bm + wave * 16 + r0;
      const int b = rowb >> 10, s = rowb & 1023;
      union { __bf16 hh[4]; unsigned long long u; } w;
#pragma unroll
      for (int i = 0; i < 4; i++) w.hh[i] = (__bf16)(acc[nj][i] + bb);
      *(unsigned long long*)(VT + (size_t)(b * 8 + h) * 65536 + (size_t)d * 1024 + s) = w.u;
    } else {
#pragma unroll
      for (int i = 0; i < 4; i++)
        Y[(size_t)(bm + wave * 16 + r0 + i) * QKVLD + col] = (__bf16)(acc[nj][i] + bb);
    }
  }
}

// ---------------------------------------------------------------------------
// R21: split-K x2 64x64-tile GEMM for the N=512 GEMMs. 1024 blocks = 4/CU.
// Two K-halves write disjoint f32 buffers; downstream LN sums h0+h1+bias.
// ---------------------------------------------------------------------------
__global__ __launch_bounds__(256, 4) void mgemm64s(
    const __bf16* __restrict__ A, const __bf16* __restrict__ W,
    float* __restrict__ Y0, float* __restrict__ Y1,
    int Kstride, int Khalf) {
  __shared__ __bf16 As[2][64 * 64];
  __shared__ __bf16 Bs[2][64 * 64];
  const int tid = threadIdx.x;
  const int wave = tid >> 6, lane = tid & 63;
  const int nwg = gridDim.x * gridDim.y;  // 1024
  const int lin = blockIdx.y * gridDim.x + blockIdx.x;
  const int swz = xcd_swz(lin, nwg);
  const int bn = (swz & 7) * 64;
  const int rest = swz >> 3;
  const int ks = rest & 1;
  const int bm = (rest >> 1) * 64;
  const int k0 = ks * Khalf;
  float* __restrict__ Y = ks ? Y1 : Y0;

  const int rsub = lane >> 3;
  const int gch = ((lane & 7) ^ rsub) * 8;
  const __bf16* gA = A + (size_t)(bm + wave * 16 + rsub) * Kstride + k0 + gch;
  const __bf16* gB = W + (size_t)(bn + wave * 16 + rsub) * Kstride + k0 + gch;

  const int mrow = lane & 15, g4 = lane >> 4;
  const int rsw = mrow & 7;
  const int wm = (wave & 1) * 32, wn = (wave >> 1) * 32;

  floatx4 acc[2][2];
#pragma unroll
  for (int mi = 0; mi < 2; mi++)
#pragma unroll
    for (int ni = 0; ni < 2; ni++) acc[mi][ni] = (floatx4){0.f, 0.f, 0.f, 0.f};

  const int nk = Khalf >> 6;
  auto stage = [&](int buf, int kt) {
    const __bf16* ga = gA + (size_t)kt * 64;
    const __bf16* gb = gB + (size_t)kt * 64;
    __bf16* la = &As[buf][wave * 16 * 64];
    __bf16* lb = &Bs[buf][wave * 16 * 64];
#pragma unroll
    for (int i = 0; i < 2; i++) {
      g2l16(ga + (size_t)(i * 8) * Kstride, la + i * 8 * 64);
      g2l16(gb + (size_t)(i * 8) * Kstride, lb + i * 8 * 64);
    }
  };

  stage(0, 0);
  int cur = 0;
  for (int kk = 0; kk < nk; kk++) {
    __syncthreads();
    if (kk + 1 < nk) stage(cur ^ 1, kk + 1);
    const __bf16* Ab = As[cur];
    const __bf16* Bb = Bs[cur];
#pragma unroll
    for (int c = 0; c < 2; c++) {
      const int pc = (((c * 4 + g4) ^ rsw)) * 8;
      bf16x8 af[2], bfr[2];
#pragma unroll
      for (int mi = 0; mi < 2; mi++)
        af[mi] = *(const bf16x8*)(Ab + (wm + mi * 16 + mrow) * 64 + pc);
#pragma unroll
      for (int ni = 0; ni < 2; ni++)
        bfr[ni] = *(const bf16x8*)(Bb + (wn + ni * 16 + mrow) * 64 + pc);
#pragma unroll
      for (int mi = 0; mi < 2; mi++)
#pragma unroll
        for (int ni = 0; ni < 2; ni++)
          acc[mi][ni] = __builtin_amdgcn_mfma_f32_16x16x32_bf16(af[mi], bfr[ni], acc[mi][ni], 0, 0, 0);
    }
    cur ^= 1;
  }

  const int cc = lane & 15;
  const int r0 = (lane >> 4) * 4;
#pragma unroll
  for (int mi = 0; mi < 2; mi++) {
#pragma unroll
    for (int ni = 0; ni < 2; ni++) {
      const int col = bn + wn + ni * 16 + cc;
#pragma unroll
      for (int i = 0; i < 4; i++) {
        const size_t row = bm + wm + mi * 16 + r0 + i;
        Y[row * 512 + col] = acc[mi][ni][i];
      }
    }
  }
}

// ---------------------------------------------------------------------------
// R25: conv GEMMs with UNIFORM makespan: all 256 blocks run nk=8 (y1: 4
// k-splits x16 bm, y2: 16x4, y3: 64x1, direct: 64). Exactly 1 block/CU.
// ---------------------------------------------------------------------------
__global__ __launch_bounds__(256, 2) void cgemm3(
    const __bf16* __restrict__ A, const __bf16* __restrict__ w4,
    const __bf16* __restrict__ w16, const __bf16* __restrict__ w64,
    const __bf16* __restrict__ w1, const float* __restrict__ cb0,
    float* __restrict__ y1, float* __restrict__ y2, float* __restrict__ y3,
    __bf16* __restrict__ msb) {
  int id = xcd_swz(blockIdx.x, 256);
  const __bf16* W;
  float* yseg = nullptr;
  int K, bm, k0;
  bool direct = false;
  if (id < 64) {
    W = w4; yseg = y1; K = 2048; bm = (id & 15) * 64; k0 = (id >> 4) * 512;
  } else if (id < 128) {
    id -= 64;
    W = w16; yseg = y2; K = 8192; bm = (id & 3) * 64; k0 = (id >> 2) * 512;
  } else if (id < 192) {
    id -= 128;
    W = w64; yseg = y3; K = 32768; bm = 0; k0 = id * 512;
  } else {
    id -= 192;
    W = w1; K = 512; bm = id * 64; k0 = 0; direct = true;
  }

  __shared__ __bf16 As[2][64 * 64];
  __shared__ __bf16 Bs[2][128 * 64];
  const int tid = threadIdx.x;
  const int wave = tid >> 6, lane = tid & 63;

  const int rsub = lane >> 3;
  const int gch = ((lane & 7) ^ rsub) * 8;
  const __bf16* gA = A + (size_t)(bm + wave * 16 + rsub) * K + k0 + gch;
  const __bf16* gB = W + (size_t)(wave * 32 + rsub) * K + k0 + gch;

  const int mrow = lane & 15, g4 = lane >> 4;
  const int rsw = mrow & 7;

  floatx4 acc[8];
#pragma unroll
  for (int nj = 0; nj < 8; nj++) acc[nj] = (floatx4){0.f, 0.f, 0.f, 0.f};

  auto stage = [&](int buf, int kt) {
    const size_t ko = (size_t)kt * 64;
#pragma unroll
    for (int i = 0; i < 2; i++)
      g2l16(gA + ko + (size_t)(i * 8) * K, &As[buf][(wave * 16 + i * 8) * 64]);
#pragma unroll
    for (int i = 0; i < 4; i++)
      g2l16(gB + ko + (size_t)(i * 8) * K, &Bs[buf][(wave * 32 + i * 8) * 64]);
  };

  stage(0, 0);
  int cur = 0;
  for (int kk = 0; kk < 8; kk++) {
    __syncthreads();
    if (kk + 1 < 8) stage(cur ^ 1, kk + 1);
    const __bf16* Ab = As[cur];
    const __bf16* Bb = Bs[cur];
#pragma unroll
    for (int c = 0; c < 2; c++) {
      const int pc = (((c * 4 + g4) ^ rsw)) * 8;
      bf16x8 af = *(const bf16x8*)(Ab + (wave * 16 + mrow) * 64 + pc);
#pragma unroll
      for (int nj = 0; nj < 8; nj++) {
        bf16x8 bfv = *(const bf16x8*)(Bb + (nj * 16 + mrow) * 64 + pc);
        acc[nj] = __builtin_amdgcn_mfma_f32_16x16x32_bf16(af, bfv, acc[nj], 0, 0, 0);
      }
    }
    cur ^= 1;
  }

  const int cc = lane & 15;
  const int r0 = (lane >> 4) * 4;
  if (direct) {
#pragma unroll
    for (int nj = 0; nj < 8; nj++) {
      const float bb = cb0[nj * 16 + cc];
#pragma unroll
      for (int i = 0; i < 4; i++)
        msb[(size_t)(bm + wave * 16 + r0 + i) * 512 + nj * 16 + cc] =
            (__bf16)(acc[nj][i] + bb);
    }
  } else {
#pragma unroll
    for (int nj = 0; nj < 8; nj++)
#pragma unroll
      for (int i = 0; i < 4; i++)
        atomicAdd(&yseg[(size_t)(bm + wave * 16 + r0 + i) * 128 + nj * 16 + cc],
                  acc[nj][i]);
  }
}

// ---------------------------------------------------------------------------
// R24: fattnP — flash attention (blocks 0..511) + non-critical prep as
// extra blocks (512..4543). Block-partition fusion (no sync).
// ---------------------------------------------------------------------------
__global__ __launch_bounds__(256) void fattnP(
    const __bf16* __restrict__ QKV, const __bf16* __restrict__ VT,
    const float* __restrict__ rbias, const int* __restrict__ rm,
    const int* __restrict__ amask, __bf16* __restrict__ O,
    const float* __restrict__ cw1, const float* __restrict__ cw2,
    const float* __restrict__ cw3, __bf16* __restrict__ wt4,
    __bf16* __restrict__ wt16, __bf16* __restrict__ wt64,
    const float* __restrict__ s4, const float* __restrict__ s5,
    const float* __restrict__ s6, const float* __restrict__ s7,
    const float* __restrict__ s8,
    __bf16* __restrict__ d4, __bf16* __restrict__ d5, __bf16* __restrict__ d6,
    __bf16* __restrict__ d7, __bf16* __restrict__ d8,
    const float* __restrict__ cb1, const float* __restrict__ cb2,
    const float* __restrict__ cb3, float* __restrict__ yall) {
  __shared__ __align__(16) char smraw[49280];
  const int tid = threadIdx.x;

  if (blockIdx.x < 512) {
    __bf16* KsB = (__bf16*)smraw;              // 2 x 4096 bf16
    __bf16* VsB = KsB + 8192;                  // 2 x 4096 bf16
    float* T = (float*)(smraw + 32768);        // 4 x 1032 f32

    const int wave = tid >> 6, lane = tid & 63;
    const int swz = xcd_swz((int)blockIdx.x, 512);
    const int qb = swz % 16;
    const int bh = swz / 16;
    const int b = bh >> 3, h = bh & 7;
    const int q0 = qb * 64;
    const int cc = lane & 15, quad = lane >> 4;

    for (int j = tid; j < 1024; j += 256) {
      const int rv = rm[b * S_ + j];
      const float mk = amask[b * S_ + j] ? 1.f : 0.f;
#pragma unroll
      for (int ri = 0; ri < 4; ri++)
        T[ri * 1032 + j] = __expf(rbias[h * 16 + ri * 4 + rv]) * mk;
    }

    const int qrow = q0 + wave * 16;
    const int rmi = rm[b * S_ + qrow + cc];
    const float* Trow = T + rmi * 1032;

    const __bf16* Qr = QKV + (size_t)(b * S_ + qrow + cc) * QKVLD + h * 64;
    const bf16x8 qb0 = *(const bf16x8*)(Qr + quad * 8);
    const bf16x8 qb1 = *(const bf16x8*)(Qr + 32 + quad * 8);

    floatx4 of[4];
#pragma unroll
    for (int dc = 0; dc < 4; dc++) of[dc] = (floatx4){0.f, 0.f, 0.f, 0.f};
    float mold = -1e30f, l = 0.f;

    const int rsub = lane >> 3;
    const int sgch = ((lane & 7) ^ rsub) * 8;
    const __bf16* Kg = QKV + (size_t)(b * S_ + wave * 16 + rsub) * QKVLD + 512 + h * 64 + sgch;
    const __bf16* Vg = VT + (size_t)bh * 65536 + (size_t)(wave * 16 + rsub) * 1024 + sgch;

    auto stage = [&](int buf, int jt) {
      const int j0 = jt * 64;
#pragma unroll
      for (int i = 0; i < 2; i++) {
        g2l16(Kg + (size_t)(j0 + i * 8) * QKVLD, KsB + buf * 4096 + (wave * 16 + i * 8) * 64);
        g2l16(Vg + j0 + (size_t)(i * 8) * 1024, VsB + buf * 4096 + (wave * 16 + i * 8) * 64);
      }
    };

    stage(0, 0);
    int cur = 0;
    const int rk = cc & 7;

    for (int jt = 0; jt < 16; jt++) {
      const int j0 = jt * 64;
      __syncthreads();
      if (jt + 1 < 16) stage(cur ^ 1, jt + 1);
      const __bf16* Kb = KsB + cur * 4096;
      const __bf16* Vb = VsB + cur * 4096;

      floatx4 st[4];
      __builtin_amdgcn_s_setprio(1);
#pragma unroll
      for (int js = 0; js < 4; js++) {
        const bf16x8 ka0 = *(const bf16x8*)(Kb + (js * 16 + cc) * 64 + ((quad ^ rk) * 8));
        const bf16x8 ka1 = *(const bf16x8*)(Kb + (js * 16 + cc) * 64 + (((quad + 4) ^ rk) * 8));
        floatx4 s = (floatx4){0.f, 0.f, 0.f, 0.f};
        s = __builtin_amdgcn_mfma_f32_16x16x32_bf16(ka0, qb0, s, 0, 0, 0);
        s = __builtin_amdgcn_mfma_f32_16x16x32_bf16(ka1, qb1, s, 0, 0, 0);
        st[js] = s;
      }
      __builtin_amdgcn_s_setprio(0);

      float mxr = st[0][0];
#pragma unroll
      for (int js = 0; js < 4; js++)
#pragma unroll
        for (int i = 0; i < 4; i++) mxr = fmaxf(mxr, st[js][i]);
      mxr = fmaxf(mxr, __shfl_xor(mxr, 16));
      mxr = fmaxf(mxr, __shfl_xor(mxr, 32));
      const float mnew = fmaxf(mold, mxr * 0.125f);
      const float alpha = __expf(mold - mnew);
      mold = mnew;

      float rsum = 0.f;
      short4v pk[4];
#pragma unroll
      for (int js = 0; js < 4; js++) {
        const floatx4 Tv = *(const floatx4*)(Trow + j0 + js * 16 + quad * 4);
        union { __bf16 hh[4]; short4v s4v; } u;
#pragma unroll
        for (int i = 0; i < 4; i++) {
          const float p = __expf(fmaf(st[js][i], 0.125f, -mnew)) * Tv[i];
          rsum += p;
          u.hh[i] = (__bf16)p;
        }
        pk[js] = u.s4v;
      }
      rsum += __shfl_xor(rsum, 16);
      rsum += __shfl_xor(rsum, 32);
      l = l * alpha + rsum;

#pragma unroll
      for (int dc = 0; dc < 4; dc++)
#pragma unroll
        for (int i = 0; i < 4; i++) of[dc][i] *= alpha;

      __builtin_amdgcn_s_setprio(1);
#pragma unroll
      for (int dc = 0; dc < 4; dc++) {
#pragma unroll
        for (int js = 0; js < 4; js++) {
          union { bf16x4 v; short4v s4v; } va;
          va.v = *(const bf16x4*)(Vb + (dc * 16 + cc) * 64 +
                                  (((js * 2 + (quad >> 1)) ^ rk) * 8) + (quad & 1) * 4);
          of[dc] = __builtin_amdgcn_mfma_f32_16x16x16bf16_1k(va.s4v, pk[js], of[dc], 0, 0, 0);
        }
      }
      __builtin_amdgcn_s_setprio(0);
      cur ^= 1;
    }

    const float invl = 1.f / l;
    __bf16* po = O + (size_t)(b * S_ + qrow + cc) * D_ + h * 64;
#pragma unroll
    for (int dc = 0; dc < 4; dc++) {
      union { __bf16 hh[4]; unsigned long long u; } w;
#pragma unroll
      for (int i = 0; i < 4; i++) w.hh[i] = (__bf16)(of[dc][i] * invl);
      *(unsigned long long*)(po + dc * 16 + quad * 4) = w.u;
    }
    return;
  }

  int pb = blockIdx.x - 512;
  if (pb < 1408) {
    float* Ts = (float*)smraw;  // 4608 f32
    int id = pb;
    const float* cw;
    __bf16* wt;
    int lg, c, d0i, TD, L;
    if (id < 128) {
      cw = cw1; wt = wt4; lg = 2; c = id; d0i = 0; TD = 512; L = 2048;
    } else if (id < 384) {
      id -= 128;
      cw = cw2; wt = wt16; lg = 4; c = id >> 1; d0i = (id & 1) * 256; TD = 256; L = 4096;
    } else {
      id -= 384;
      cw = cw3; wt = wt64; lg = 6; c = id >> 3; d0i = (id & 7) * 64; TD = 64; L = 4096;
    }
    const int sc = 1 << lg;
    const int KD = 512 << lg;
    const float* src = cw + (size_t)c * KD + (size_t)d0i * sc;

    for (int f = tid * 4; f < L; f += 1024) {
      const float4 v = *(const float4*)(src + f);
      const float vv[4] = {v.x, v.y, v.z, v.w};
#pragma unroll
      for (int j = 0; j < 4; j++) {
        const int idx = f + j;
        const int dl = idx >> lg, k = idx & (sc - 1);
        Ts[dl * (sc + 1) + k] = vv[j];
      }
    }
    __syncthreads();

    for (int w = tid * 8; w < L; w += 2048) {
      const int kpos = w / TD;
      const int dl0 = w - kpos * TD;
      union { __bf16 hh[8]; bf16x8 v; } u;
#pragma unroll
      for (int j = 0; j < 8; j++)
        u.hh[j] = (__bf16)Ts[(dl0 + j) * (sc + 1) + kpos];
      *(bf16x8*)(wt + (size_t)c * KD + kpos * 512 + d0i + dl0) = u.v;
    }
    return;
  }

  const int qd = (pb - 1408) * 256 + tid;
  if (qd < 172032) {  // seed conv outputs with bias (cgemm3 atomically adds)
    float bb;
    if (qd < 131072) bb = cb1[qd & 127];
    else if (qd < 163840) bb = cb2[qd & 127];
    else bb = cb3[qd & 127];
    yall[qd] = bb;
  }
  const float* src;
  __bf16* dst;
  int base;
  if (qd < 65536) { src = s4; dst = d4; base = 0; }
  else if (qd < 131072) { src = s5; dst = d5; base = 65536; }
  else if (qd < 147456) { src = s6; dst = d6; base = 131072; }
  else if (qd < 409600) { src = s7; dst = d7; base = 147456; }
  else { src = s8; dst = d8; base = 409600; }
  const int local = qd - base;
  float4 v = *(const float4*)(src + (size_t)local * 4);
  union { __bf16 h[4]; unsigned long long u; } t;
  t.h[0] = (__bf16)v.x; t.h[1] = (__bf16)v.y;
  t.h[2] = (__bf16)v.z; t.h[3] = (__bf16)v.w;
  *(unsigned long long*)(dst + (size_t)local * 4) = t.u;
}

// ---------------------------------------------------------------------------
// R21: LN kernels take TWO GEMM partials + a bias vector (split-K sum + bias
// folded in): v = xa + h0 + h1 + bias[col].
// ---------------------------------------------------------------------------
__global__ __launch_bounds__(256) void add_ln_kernel(
    const float* __restrict__ xa, const float* __restrict__ h0,
    const float* __restrict__ h1, const float* __restrict__ bias,
    const float* __restrict__ g, const float* __restrict__ be,
    float* __restrict__ out, __bf16* __restrict__ outb) {
  const int row = (blockIdx.x * 256 + threadIdx.x) >> 6;
  const int lane = threadIdx.x & 63;
  const floatx4* pa = (const floatx4*)(xa + (size_t)row * D_);
  const floatx4* p0 = (const floatx4*)(h0 + (size_t)row * D_);
  const floatx4* p1 = (const floatx4*)(h1 + (size_t)row * D_);
  floatx4 v[2];
  float sum = 0.f;
#pragma unroll
  for (int i = 0; i < 2; i++) {
    const int dd = lane + 64 * i;
    v[i] = pa[dd] + p0[dd] + p1[dd] + ((const floatx4*)bias)[dd];
    sum += v[i][0] + v[i][1] + v[i][2] + v[i][3];
  }
#pragma unroll
  for (int off = 32; off; off >>= 1) sum += __shfl_xor(sum, off);
  const float mu = sum * (1.f / D_);
  float vs = 0.f;
#pragma unroll
  for (int i = 0; i < 2; i++)
#pragma unroll
    for (int j = 0; j < 4; j++) { float t = v[i][j] - mu; vs += t * t; }
#pragma unroll
  for (int off = 32; off; off >>= 1) vs += __shfl_xor(vs, off);
  const float inv = rsqrtf(vs * (1.f / D_) + 1e-5f);
  floatx4* po = (floatx4*)(out + (size_t)row * D_);
#pragma unroll
  for (int i = 0; i < 2; i++) {
    const int dd = lane + 64 * i;
    const floatx4 g4 = ((const floatx4*)g)[dd];
    const floatx4 b4 = ((const floatx4*)be)[dd];
    const floatx4 o = (v[i] - mu) * inv * g4 + b4;
    po[dd] = o;
    if (outb) {
      union { __bf16 hh[4]; unsigned long long u; } w;
#pragma unroll
      for (int j = 0; j < 4; j++) w.hh[j] = (__bf16)o[j];
      *(unsigned long long*)(outb + (size_t)row * D_ + dd * 4) = w.u;
    }
  }
}

__global__ __launch_bounds__(256) void ln_chain_kernel(
    const float* __restrict__ x1, const float* __restrict__ h0,
    const float* __restrict__ h1, const float* __restrict__ bias,
    const float* __restrict__ ltg, const float* __restrict__ ltb,
    const float* __restrict__ n2g, const float* __restrict__ n2b,
    float* __restrict__ out, __bf16* __restrict__ outb) {
  const int row = (blockIdx.x * 256 + threadIdx.x) >> 6;
  const int lane = threadIdx.x & 63;
  const floatx4* p1 = (const floatx4*)(x1 + (size_t)row * D_);
  const floatx4* pf0 = (const floatx4*)(h0 + (size_t)row * D_);
  const floatx4* pf1 = (const floatx4*)(h1 + (size_t)row * D_);
  floatx4 xv[2], u[2];
  float sum = 0.f;
#pragma unroll
  for (int i = 0; i < 2; i++) {
    const int dd = lane + 64 * i;
    xv[i] = p1[dd];
    u[i] = xv[i] + pf0[dd] + pf1[dd] + ((const floatx4*)bias)[dd];
    sum += u[i][0] + u[i][1] + u[i][2] + u[i][3];
  }
#pragma unroll
  for (int off = 32; off; off >>= 1) sum += __shfl_xor(sum, off);
  float mu = sum * (1.f / D_);
  float vs = 0.f;
#pragma unroll
  for (int i = 0; i < 2; i++)
#pragma unroll
    for (int j = 0; j < 4; j++) { float t = u[i][j] - mu; vs += t * t; }
#pragma unroll
  for (int off = 32; off; off >>= 1) vs += __shfl_xor(vs, off);
  float inv = rsqrtf(vs * (1.f / D_) + 1e-5f);
  float sum2 = 0.f;
#pragma unroll
  for (int i = 0; i < 2; i++) {
    const int dd = lane + 64 * i;
    const floatx4 g4 = ((const floatx4*)ltg)[dd];
    const floatx4 b4 = ((const floatx4*)ltb)[dd];
    u[i] = xv[i] + ((u[i] - mu) * inv * g4 + b4);
    sum2 += u[i][0] + u[i][1] + u[i][2] + u[i][3];
  }
#pragma unroll
  for (int off = 32; off; off >>= 1) sum2 += __shfl_xor(sum2, off);
  float mu2 = sum2 * (1.f / D_);
  float vs2 = 0.f;
#pragma unroll
  for (int i = 0; i < 2; i++)
#pragma unroll
    for (int j = 0; j < 4; j++) { float t = u[i][j] - mu2; vs2 += t * t; }
#pragma unroll
  for (int off = 32; off; off >>= 1) vs2 += __shfl_xor(vs2, off);
  float inv2 = rsqrtf(vs2 * (1.f / D_) + 1e-5f);
  floatx4* po = (floatx4*)(out + (size_t)row * D_);
#pragma unroll
  for (int i = 0; i < 2; i++) {
    const int dd = lane + 64 * i;
    const floatx4 g4 = ((const floatx4*)n2g)[dd];
    const floatx4 b4 = ((const floatx4*)n2b)[dd];
    const floatx4 o = (u[i] - mu2) * inv2 * g4 + b4;
    po[dd] = o;
    union { __bf16 hh[4]; unsigned long long u8; } w;
#pragma unroll
    for (int j = 0; j < 4; j++) w.hh[j] = (__bf16)o[j];
    *(unsigned long long*)(outb + (size_t)row * D_ + dd * 4) = w.u8;
  }
}

// ---------------------------------------------------------------------------
// R20: interp vectorized x4 along channels.
// ---------------------------------------------------------------------------
__global__ void interp_kernel(const float* __restrict__ y1, const float* __restrict__ y2,
                              const float* __restrict__ y3, __bf16* __restrict__ ms) {
  int idx = blockIdx.x * 256 + threadIdx.x;
  if (idx >= B_ * S_ * 3 * C_ / 4) return;
  const int c3_4 = idx % 96;
  const int rest = idx / 96;
  const int s = rest & 1023, b = rest >> 10;
  const int i = c3_4 >> 5;
  const int c = (c3_4 & 31) * 4;
  const int Lin = (i == 0) ? 256 : (i == 1) ? 64 : 16;
  const float* y = (i == 0) ? y1 : (i == 1) ? y2 : y3;
  float pos = (s + 0.5f) * ((float)Lin / S_) - 0.5f;
  pos = fminf(fmaxf(pos, 0.f), (float)(Lin - 1));
  const int lo = (int)floorf(pos);
  const int hi = min(lo + 1, Lin - 1);
  const float w = pos - (float)lo;
  const float* ybase = y + ((size_t)(b * Lin + lo)) * 128 + c;
  const floatx4 vlo = *(const floatx4*)ybase;
  const floatx4 vhi = *(const floatx4*)(ybase + (size_t)(hi - lo) * 128);
  const floatx4 o = vlo * (1.f - w) + vhi * w;
  union { __bf16 hh[4]; unsigned long long u; } t;
#pragma unroll
  for (int j = 0; j < 4; j++) t.hh[j] = (__bf16)o[j];
  *(unsigned long long*)(ms + ((size_t)b * S_ + s) * D_ + C_ + i * 128 + c) = t.u;
}

// ---------------------------------------------------------------------------
extern "C" void kernel_launch(void* const* d_in, const int* in_sizes, int n_in,
                              void* d_out, int out_size, void* d_ws, size_t ws_size,
                              hipStream_t stream) {
  const float* x   = (const float*)d_in[0];
  const int* rm    = (const int*)d_in[1];
  const int* am    = (const int*)d_in[2];
  const float* wq  = (const float*)d_in[3];
  const float* bq  = (const float*)d_in[4];
  const float* wk  = (const float*)d_in[5];
  const float* bk  = (const float*)d_in[6];
  const float* wv  = (const float*)d_in[7];
  const float* bv  = (const float*)d_in[8];
  const float* wo  = (const float*)d_in[9];
  const float* bo  = (const float*)d_in[10];
  const float* rbias = (const float*)d_in[11];
  const float* cw0 = (const float*)d_in[12];
  const float* cb0 = (const float*)d_in[13];
  const float* cw1 = (const float*)d_in[14];
  const float* cb1 = (const float*)d_in[15];
  const float* cw2 = (const float*)d_in[16];
  const float* cb2 = (const float*)d_in[17];
  const float* cw3 = (const float*)d_in[18];
  const float* cb3 = (const float*)d_in[19];
  const float* fw  = (const float*)d_in[20];
  const float* fb  = (const float*)d_in[21];
  const float* ltg = (const float*)d_in[22];
  const float* ltb = (const float*)d_in[23];
  const float* n1g = (const float*)d_in[24];
  const float* n1b = (const float*)d_in[25];
  const float* n2g = (const float*)d_in[26];
  const float* n2b = (const float*)d_in[27];
  const float* fw1 = (const float*)d_in[28];
  const float* fb1 = (const float*)d_in[29];
  const float* fw2 = (const float*)d_in[30];
  const float* fb2 = (const float*)d_in[31];
  const float* n3g = (const float*)d_in[32];
  const float* n3b = (const float*)d_in[33];

  float* ws = (float*)d_ws;
  __bf16* wob   = (__bf16*)(ws + 393216);    // 256K
  __bf16* fwb   = (__bf16*)(ws + 524288);    // 256K
  __bf16* cw0b  = (__bf16*)(ws + 655360);    // 64K
  __bf16* fw1b  = (__bf16*)(ws + 688128);    // 1M
  __bf16* fw2b  = (__bf16*)(ws + 1212416);   // 1M
  __bf16* qkv   = (__bf16*)(ws + 2883584);   // 6M elems [dead after attn]
  __bf16* attnb = (__bf16*)(ws + 6029312);   // 2M elems [dead after wo gemm]
  float*  x1    = ws + 7077888;              // 2M f [dead after ln_chain]
  __bf16* x1b   = (__bf16*)(ws + 9175040);   // 2M elems
  float*  scr   = ws + 10223616;             // 2M f
  float*  x2    = ws + 12320768;             // 2M f
  __bf16* x2b   = (__bf16*)(ws + 14417920);  // 2M elems
  __bf16* msb   = (__bf16*)(ws + 15466496);  // 2M elems
  float*  y1    = ws + 16515072;             // 131072 f (t-major 1024x128)
  float*  y2    = ws + 16646144;             // 32768 f
  float*  y3    = ws + 16678912;             // 8192 f
  __bf16* wt4b  = (__bf16*)(ws + 16689152);  // 262144 elems
  __bf16* wt16b = (__bf16*)(ws + 16820224);  // 1048576 elems
  __bf16* wt64b = (__bf16*)(ws + 17344512);  // 4194304 elems
  // overlays (lifetime-disjoint):
  __bf16* VT    = (__bf16*)(ws + 10223616);  // 2M elems over scr (attn phase)
  __bf16* ffh   = (__bf16*)(ws + 2883584);   // 8M elems over qkv+attnb (FFN phase)
  float*  h1a   = ws + 2883584;              // 2M f over qkv (wo/fuse split-K half-1)

  dim3 blk(256);

  // R26: qkv GEMM reads f32 inputs directly (prepA dispatch eliminated)
  mgemm_qkv<<<768, blk, 0, stream>>>(x, wq, wk, wv, bq, bk, bv, qkv, VT);

  // fattn (512 blocks) + non-critical prep (4032 blocks) in ONE dispatch
  fattnP<<<4544, blk, 0, stream>>>(
      qkv, VT, rbias, rm, am, attnb,
      cw1, cw2, cw3, wt4b, wt16b, wt64b,
      wo, fw, cw0, fw1, fw2,
      wob, fwb, cw0b, fw1b, fw2b,
      cb1, cb2, cb3, y1);

  // wo projection: split-K (2x256) -> scr + h1a (qkv region is dead now)
  mgemm64s<<<dim3(8, 128), blk, 0, stream>>>(attnb, wob, scr, h1a, 512, 256);
  add_ln_kernel<<<1024, blk, 0, stream>>>(x, scr, h1a, bo, n1g, n1b, x1, x1b);

  cgemm3<<<256, blk, 0, stream>>>(x1b, wt4b, wt16b, wt64b, cw0b, cb0, y1, y2, y3, msb);
  interp_kernel<<<1536, blk, 0, stream>>>(y1, y2, y3, msb);

  // fuse GEMM: split-K (2x256) -> scr + h1a
  mgemm64s<<<dim3(8, 128), blk, 0, stream>>>(msb, fwb, scr, h1a, 512, 256);
  ln_chain_kernel<<<1024, blk, 0, stream>>>(x1, scr, h1a, fb, ltg, ltb, n2g, n2b, x2, x2b);

  mgemm<true, true, false><<<dim3(16, 32), blk, 0, stream>>>(
      x2b, fw1b, fb1, ffh, 4096, 2048, 512, 2048, nullptr);
  // ffn2: split-K (2x1024; scr + x1 are dead f32 buffers; x1 starts exactly
  // at ffh's end so no overlap with the live ffh input)
  mgemm64s<<<dim3(8, 128), blk, 0, stream>>>(ffh, fw2b, scr, x1, 2048, 1024);
  add_ln_kernel<<<1024, blk, 0, stream>>>(x2, scr, x1, fb2, n3g, n3b, (float*)d_out, nullptr);
}

// Round 10
// 257.658 us; speedup vs baseline: 1.0921x; 1.0921x over previous
//
#include <hip/hip_runtime.h>
#include <math.h>

constexpr int B_ = 4, S_ = 1024, D_ = 512, H_ = 8, FF_ = 2048;
constexpr int DK_ = 64;
constexpr int C_ = 128;
constexpr int QKVLD = 1536;  // qkv buffer row stride (q|k|v)

typedef __bf16 bf16x8 __attribute__((ext_vector_type(8)));
typedef __bf16 bf16x4 __attribute__((ext_vector_type(4)));
typedef short short4v __attribute__((ext_vector_type(4)));
typedef float floatx4 __attribute__((ext_vector_type(4)));

// R18: direct global->LDS DMA (dwordx4). LDS dest is wave-uniform base +
// lane*16B (linear); swizzle achieved by pre-swizzling the per-lane GLOBAL
// source address (guide rule #21).
__device__ __forceinline__ void g2l16(const __bf16* g, __bf16* l) {
  __builtin_amdgcn_global_load_lds(
      (__attribute__((address_space(1))) void*)(unsigned long long)g,
      (__attribute__((address_space(3))) void*)(unsigned int)(unsigned long long)l,
      16, 0, 0);
}

// R19: XCD-aware bijective block swizzle (T1). Requires nwg%8==0.
__device__ __forceinline__ int xcd_swz(int lin, int nwg) {
  return (lin & 7) * (nwg >> 3) + (lin >> 3);
}

// ---------------------------------------------------------------------------
// bf16 MFMA GEMM, BK=64, 128x128 tile (ffn1 only now). global_load_lds
// staging, double-buffered LDS, ONE barrier per K-step.
// ---------------------------------------------------------------------------
template <bool OUTBF16, bool RELU, bool WRITEVT>
__global__ __launch_bounds__(256, 2) void mgemm(
    const __bf16* __restrict__ A, const __bf16* __restrict__ W,
    const float* __restrict__ bias, void* __restrict__ Yv,
    int M, int N, int K, int ldY, __bf16* __restrict__ VT) {
  __shared__ __bf16 As[2][128 * 64];
  __shared__ __bf16 Bs[2][128 * 64];
  const int tid = threadIdx.x;
  const int wave = tid >> 6, lane = tid & 63;
  const int nwg = gridDim.x * gridDim.y;
  const int lin = blockIdx.y * gridDim.x + blockIdx.x;
  const int swz = xcd_swz(lin, nwg);
  const int bm = (swz / gridDim.x) * 128, bn = (swz % gridDim.x) * 128;

  const int rsub = lane >> 3;
  const int gch = ((lane & 7) ^ rsub) * 8;
  const __bf16* gA = A + (size_t)(bm + wave * 32 + rsub) * K + gch;
  const __bf16* gB = W + (size_t)(bn + wave * 32 + rsub) * K + gch;

  const int mrow = lane & 15, g4 = lane >> 4;
  const int rsw = mrow & 7;
  const int wm = (wave & 1) * 64, wn = (wave >> 1) * 64;

  floatx4 acc[4][4];
#pragma unroll
  for (int mi = 0; mi < 4; mi++)
#pragma unroll
    for (int ni = 0; ni < 4; ni++) acc[mi][ni] = (floatx4){0.f, 0.f, 0.f, 0.f};

  const int nk = K >> 6;
  auto stage = [&](int buf, int kt) {
    const __bf16* ga = gA + (size_t)kt * 64;
    const __bf16* gb = gB + (size_t)kt * 64;
    __bf16* la = &As[buf][wave * 32 * 64];
    __bf16* lb = &Bs[buf][wave * 32 * 64];
#pragma unroll
    for (int i = 0; i < 4; i++) {
      g2l16(ga + (size_t)(i * 8) * K, la + i * 8 * 64);
      g2l16(gb + (size_t)(i * 8) * K, lb + i * 8 * 64);
    }
  };

  stage(0, 0);
  int cur = 0;
  for (int kk = 0; kk < nk; kk++) {
    __syncthreads();
    if (kk + 1 < nk) stage(cur ^ 1, kk + 1);
    const __bf16* Ab = As[cur];
    const __bf16* Bb = Bs[cur];
#pragma unroll
    for (int c = 0; c < 2; c++) {
      const int pc = (((c * 4 + g4) ^ rsw)) * 8;
      bf16x8 af[4], bfr[4];
#pragma unroll
      for (int mi = 0; mi < 4; mi++)
        af[mi] = *(const bf16x8*)(Ab + (wm + mi * 16 + mrow) * 64 + pc);
#pragma unroll
      for (int ni = 0; ni < 4; ni++)
        bfr[ni] = *(const bf16x8*)(Bb + (wn + ni * 16 + mrow) * 64 + pc);
#pragma unroll
      for (int mi = 0; mi < 4; mi++)
#pragma unroll
        for (int ni = 0; ni < 4; ni++)
          acc[mi][ni] = __builtin_amdgcn_mfma_f32_16x16x32_bf16(af[mi], bfr[ni], acc[mi][ni], 0, 0, 0);
    }
    cur ^= 1;
  }

  const int cc = lane & 15;
  const int r0 = (lane >> 4) * 4;
  float bv[4];
#pragma unroll
  for (int ni = 0; ni < 4; ni++) bv[ni] = bias[bn + wn + ni * 16 + cc];
#pragma unroll
  for (int mi = 0; mi < 4; mi++) {
#pragma unroll
    for (int ni = 0; ni < 4; ni++) {
      const int col = bn + wn + ni * 16 + cc;
      if (WRITEVT && col >= 1024) {
        const int h = (col - 1024) >> 6, d = (col - 1024) & 63;
        const int rowb = bm + wm + mi * 16 + r0;
        const int b = rowb >> 10, s = rowb & 1023;
        union { __bf16 hh[4]; unsigned long long u; } w;
#pragma unroll
        for (int i = 0; i < 4; i++) w.hh[i] = (__bf16)(acc[mi][ni][i] + bv[ni]);
        *(unsigned long long*)(VT + (size_t)(b * 8 + h) * 65536 + (size_t)d * 1024 + s) = w.u;
      } else {
#pragma unroll
        for (int i = 0; i < 4; i++) {
          float v = acc[mi][ni][i] + bv[ni];
          if (RELU) v = fmaxf(v, 0.f);
          const size_t row = bm + wm + mi * 16 + r0 + i;
          if (OUTBF16)
            ((__bf16*)Yv)[row * ldY + col] = (__bf16)v;
          else
            ((float*)Yv)[row * ldY + col] = v;
        }
      }
    }
  }
}

// ---------------------------------------------------------------------------
// R25: qkv GEMM retiled to 64x128 tiles -> 768 blocks at LB(256,3) =
// exactly 3 full rounds on 256 CUs. g2l16 double-buffered staging.
// ---------------------------------------------------------------------------
__global__ __launch_bounds__(256, 3) void mgemm_qkv(
    const __bf16* __restrict__ A, const __bf16* __restrict__ W,
    const float* __restrict__ bias, __bf16* __restrict__ Y,
    __bf16* __restrict__ VT) {
  __shared__ __bf16 As[2][64 * 64];
  __shared__ __bf16 Bs[2][128 * 64];
  const int tid = threadIdx.x;
  const int wave = tid >> 6, lane = tid & 63;
  const int swz = xcd_swz((int)blockIdx.x, 768);
  const int bm = (swz / 12) * 64, bn = (swz % 12) * 128;
  const int K = 512;

  const int rsub = lane >> 3;
  const int gch = ((lane & 7) ^ rsub) * 8;
  const __bf16* gA = A + (size_t)(bm + wave * 16 + rsub) * K + gch;
  const __bf16* gB = W + (size_t)(bn + wave * 32 + rsub) * K + gch;

  const int mrow = lane & 15, g4 = lane >> 4;
  const int rsw = mrow & 7;

  floatx4 acc[8];
#pragma unroll
  for (int nj = 0; nj < 8; nj++) acc[nj] = (floatx4){0.f, 0.f, 0.f, 0.f};

  auto stage = [&](int buf, int kt) {
    const size_t ko = (size_t)kt * 64;
#pragma unroll
    for (int i = 0; i < 2; i++)
      g2l16(gA + ko + (size_t)(i * 8) * K, &As[buf][(wave * 16 + i * 8) * 64]);
#pragma unroll
    for (int i = 0; i < 4; i++)
      g2l16(gB + ko + (size_t)(i * 8) * K, &Bs[buf][(wave * 32 + i * 8) * 64]);
  };

  stage(0, 0);
  int cur = 0;
  for (int kk = 0; kk < 8; kk++) {
    __syncthreads();
    if (kk + 1 < 8) stage(cur ^ 1, kk + 1);
    const __bf16* Ab = As[cur];
    const __bf16* Bb = Bs[cur];
#pragma unroll
    for (int c = 0; c < 2; c++) {
      const int pc = (((c * 4 + g4) ^ rsw)) * 8;
      bf16x8 af = *(const bf16x8*)(Ab + (wave * 16 + mrow) * 64 + pc);
#pragma unroll
      for (int nj = 0; nj < 8; nj++) {
        bf16x8 bfv = *(const bf16x8*)(Bb + (nj * 16 + mrow) * 64 + pc);
        acc[nj] = __builtin_amdgcn_mfma_f32_16x16x32_bf16(af, bfv, acc[nj], 0, 0, 0);
      }
    }
    cur ^= 1;
  }

  const int cc = lane & 15;
  const int r0 = (lane >> 4) * 4;
#pragma unroll
  for (int nj = 0; nj < 8; nj++) {
    const int col = bn + nj * 16 + cc;
    const float bb = bias[col];
    if (col >= 1024) {
      const int h = (col - 1024) >> 6, d = (col - 1024) & 63;
      const int rowb = bm + wave * 16 + r0;
      const int b = rowb >> 10, s = rowb & 1023;
      union { __bf16 hh[4]; unsigned long long u; } w;
#pragma unroll
      for (int i = 0; i < 4; i++) w.hh[i] = (__bf16)(acc[nj][i] + bb);
      *(unsigned long long*)(VT + (size_t)(b * 8 + h) * 65536 + (size_t)d * 1024 + s) = w.u;
    } else {
#pragma unroll
      for (int i = 0; i < 4; i++)
        Y[(size_t)(bm + wave * 16 + r0 + i) * QKVLD + col] = (__bf16)(acc[nj][i] + bb);
    }
  }
}

// ---------------------------------------------------------------------------
// R21: split-K x2 64x64-tile GEMM for the N=512 GEMMs. 1024 blocks = 4/CU.
// Two K-halves write disjoint f32 buffers; downstream LN sums h0+h1+bias.
// ---------------------------------------------------------------------------
__global__ __launch_bounds__(256, 4) void mgemm64s(
    const __bf16* __restrict__ A, const __bf16* __restrict__ W,
    float* __restrict__ Y0, float* __restrict__ Y1,
    int Kstride, int Khalf) {
  __shared__ __bf16 As[2][64 * 64];
  __shared__ __bf16 Bs[2][64 * 64];
  const int tid = threadIdx.x;
  const int wave = tid >> 6, lane = tid & 63;
  const int nwg = gridDim.x * gridDim.y;  // 1024
  const int lin = blockIdx.y * gridDim.x + blockIdx.x;
  const int swz = xcd_swz(lin, nwg);
  const int bn = (swz & 7) * 64;
  const int rest = swz >> 3;
  const int ks = rest & 1;
  const int bm = (rest >> 1) * 64;
  const int k0 = ks * Khalf;
  float* __restrict__ Y = ks ? Y1 : Y0;

  const int rsub = lane >> 3;
  const int gch = ((lane & 7) ^ rsub) * 8;
  const __bf16* gA = A + (size_t)(bm + wave * 16 + rsub) * Kstride + k0 + gch;
  const __bf16* gB = W + (size_t)(bn + wave * 16 + rsub) * Kstride + k0 + gch;

  const int mrow = lane & 15, g4 = lane >> 4;
  const int rsw = mrow & 7;
  const int wm = (wave & 1) * 32, wn = (wave >> 1) * 32;

  floatx4 acc[2][2];
#pragma unroll
  for (int mi = 0; mi < 2; mi++)
#pragma unroll
    for (int ni = 0; ni < 2; ni++) acc[mi][ni] = (floatx4){0.f, 0.f, 0.f, 0.f};

  const int nk = Khalf >> 6;
  auto stage = [&](int buf, int kt) {
    const __bf16* ga = gA + (size_t)kt * 64;
    const __bf16* gb = gB + (size_t)kt * 64;
    __bf16* la = &As[buf][wave * 16 * 64];
    __bf16* lb = &Bs[buf][wave * 16 * 64];
#pragma unroll
    for (int i = 0; i < 2; i++) {
      g2l16(ga + (size_t)(i * 8) * Kstride, la + i * 8 * 64);
      g2l16(gb + (size_t)(i * 8) * Kstride, lb + i * 8 * 64);
    }
  };

  stage(0, 0);
  int cur = 0;
  for (int kk = 0; kk < nk; kk++) {
    __syncthreads();
    if (kk + 1 < nk) stage(cur ^ 1, kk + 1);
    const __bf16* Ab = As[cur];
    const __bf16* Bb = Bs[cur];
#pragma unroll
    for (int c = 0; c < 2; c++) {
      const int pc = (((c * 4 + g4) ^ rsw)) * 8;
      bf16x8 af[2], bfr[2];
#pragma unroll
      for (int mi = 0; mi < 2; mi++)
        af[mi] = *(const bf16x8*)(Ab + (wm + mi * 16 + mrow) * 64 + pc);
#pragma unroll
      for (int ni = 0; ni < 2; ni++)
        bfr[ni] = *(const bf16x8*)(Bb + (wn + ni * 16 + mrow) * 64 + pc);
#pragma unroll
      for (int mi = 0; mi < 2; mi++)
#pragma unroll
        for (int ni = 0; ni < 2; ni++)
          acc[mi][ni] = __builtin_amdgcn_mfma_f32_16x16x32_bf16(af[mi], bfr[ni], acc[mi][ni], 0, 0, 0);
    }
    cur ^= 1;
  }

  const int cc = lane & 15;
  const int r0 = (lane >> 4) * 4;
#pragma unroll
  for (int mi = 0; mi < 2; mi++) {
#pragma unroll
    for (int ni = 0; ni < 2; ni++) {
      const int col = bn + wn + ni * 16 + cc;
#pragma unroll
      for (int i = 0; i < 4; i++) {
        const size_t row = bm + wm + mi * 16 + r0 + i;
        Y[row * 512 + col] = acc[mi][ni][i];
      }
    }
  }
}

// ---------------------------------------------------------------------------
// R25: conv GEMMs with UNIFORM makespan: all 256 blocks run nk=8 (y1: 4
// k-splits x16 bm, y2: 16x4, y3: 64x1, direct: 64). Exactly 1 block/CU.
// ---------------------------------------------------------------------------
__global__ __launch_bounds__(256, 2) void cgemm3(
    const __bf16* __restrict__ A, const __bf16* __restrict__ w4,
    const __bf16* __restrict__ w16, const __bf16* __restrict__ w64,
    const __bf16* __restrict__ w1, const float* __restrict__ cb0,
    float* __restrict__ y1, float* __restrict__ y2, float* __restrict__ y3,
    __bf16* __restrict__ msb) {
  int id = xcd_swz(blockIdx.x, 256);
  const __bf16* W;
  float* yseg = nullptr;
  int K, bm, k0;
  bool direct = false;
  if (id < 64) {
    W = w4; yseg = y1; K = 2048; bm = (id & 15) * 64; k0 = (id >> 4) * 512;
  } else if (id < 128) {
    id -= 64;
    W = w16; yseg = y2; K = 8192; bm = (id & 3) * 64; k0 = (id >> 2) * 512;
  } else if (id < 192) {
    id -= 128;
    W = w64; yseg = y3; K = 32768; bm = 0; k0 = id * 512;
  } else {
    id -= 192;
    W = w1; K = 512; bm = id * 64; k0 = 0; direct = true;
  }

  __shared__ __bf16 As[2][64 * 64];
  __shared__ __bf16 Bs[2][128 * 64];
  const int tid = threadIdx.x;
  const int wave = tid >> 6, lane = tid & 63;

  const int rsub = lane >> 3;
  const int gch = ((lane & 7) ^ rsub) * 8;
  const __bf16* gA = A + (size_t)(bm + wave * 16 + rsub) * K + k0 + gch;
  const __bf16* gB = W + (size_t)(wave * 32 + rsub) * K + k0 + gch;

  const int mrow = lane & 15, g4 = lane >> 4;
  const int rsw = mrow & 7;

  floatx4 acc[8];
#pragma unroll
  for (int nj = 0; nj < 8; nj++) acc[nj] = (floatx4){0.f, 0.f, 0.f, 0.f};

  auto stage = [&](int buf, int kt) {
    const size_t ko = (size_t)kt * 64;
#pragma unroll
    for (int i = 0; i < 2; i++)
      g2l16(gA + ko + (size_t)(i * 8) * K, &As[buf][(wave * 16 + i * 8) * 64]);
#pragma unroll
    for (int i = 0; i < 4; i++)
      g2l16(gB + ko + (size_t)(i * 8) * K, &Bs[buf][(wave * 32 + i * 8) * 64]);
  };

  stage(0, 0);
  int cur = 0;
  for (int kk = 0; kk < 8; kk++) {
    __syncthreads();
    if (kk + 1 < 8) stage(cur ^ 1, kk + 1);
    const __bf16* Ab = As[cur];
    const __bf16* Bb = Bs[cur];
#pragma unroll
    for (int c = 0; c < 2; c++) {
      const int pc = (((c * 4 + g4) ^ rsw)) * 8;
      bf16x8 af = *(const bf16x8*)(Ab + (wave * 16 + mrow) * 64 + pc);
#pragma unroll
      for (int nj = 0; nj < 8; nj++) {
        bf16x8 bfv = *(const bf16x8*)(Bb + (nj * 16 + mrow) * 64 + pc);
        acc[nj] = __builtin_amdgcn_mfma_f32_16x16x32_bf16(af, bfv, acc[nj], 0, 0, 0);
      }
    }
    cur ^= 1;
  }

  const int cc = lane & 15;
  const int r0 = (lane >> 4) * 4;
  if (direct) {
#pragma unroll
    for (int nj = 0; nj < 8; nj++) {
      const float bb = cb0[nj * 16 + cc];
#pragma unroll
      for (int i = 0; i < 4; i++)
        msb[(size_t)(bm + wave * 16 + r0 + i) * 512 + nj * 16 + cc] =
            (__bf16)(acc[nj][i] + bb);
    }
  } else {
#pragma unroll
    for (int nj = 0; nj < 8; nj++)
#pragma unroll
      for (int i = 0; i < 4; i++)
        atomicAdd(&yseg[(size_t)(bm + wave * 16 + r0 + i) * 128 + nj * 16 + cc],
                  acc[nj][i]);
  }
}

// ---------------------------------------------------------------------------
// R24: prepA — ONLY the qkv-critical prep: x cast, wq/wk/wv casts, bqkv.
// ---------------------------------------------------------------------------
__global__ void prepA(
    const float* __restrict__ x, const float* __restrict__ wq,
    const float* __restrict__ wk, const float* __restrict__ wv,
    __bf16* __restrict__ xb, __bf16* __restrict__ wqb,
    __bf16* __restrict__ wkb, __bf16* __restrict__ wvb,
    const float* __restrict__ bq, const float* __restrict__ bk,
    const float* __restrict__ bv, float* __restrict__ bqkv) {
  const int qd = blockIdx.x * 256 + threadIdx.x;
  if (qd < 384) {
    const int i = qd * 4;
    const float* s;
    int off;
    if (i < 512) { s = bq; off = 0; }
    else if (i < 1024) { s = bk; off = 512; }
    else { s = bv; off = 1024; }
    *(float4*)(bqkv + i) = *(const float4*)(s + i - off);
  }
  const float* src;
  __bf16* dst;
  int base;
  if (qd < 524288) { src = x; dst = xb; base = 0; }
  else if (qd < 589824) { src = wq; dst = wqb; base = 524288; }
  else if (qd < 655360) { src = wk; dst = wkb; base = 589824; }
  else { src = wv; dst = wvb; base = 655360; }
  const int local = qd - base;
  float4 v = *(const float4*)(src + (size_t)local * 4);
  union { __bf16 h[4]; unsigned long long u; } t;
  t.h[0] = (__bf16)v.x; t.h[1] = (__bf16)v.y;
  t.h[2] = (__bf16)v.z; t.h[3] = (__bf16)v.w;
  *(unsigned long long*)(dst + (size_t)local * 4) = t.u;
}

// ---------------------------------------------------------------------------
// R24: fattnP — flash attention (blocks 0..511) + non-critical prep as
// extra blocks (512..4543). Block-partition fusion (no sync).
// ---------------------------------------------------------------------------
__global__ __launch_bounds__(256) void fattnP(
    const __bf16* __restrict__ QKV, const __bf16* __restrict__ VT,
    const float* __restrict__ rbias, const int* __restrict__ rm,
    const int* __restrict__ amask, __bf16* __restrict__ O,
    const float* __restrict__ cw1, const float* __restrict__ cw2,
    const float* __restrict__ cw3, __bf16* __restrict__ wt4,
    __bf16* __restrict__ wt16, __bf16* __restrict__ wt64,
    const float* __restrict__ s4, const float* __restrict__ s5,
    const float* __restrict__ s6, const float* __restrict__ s7,
    const float* __restrict__ s8,
    __bf16* __restrict__ d4, __bf16* __restrict__ d5, __bf16* __restrict__ d6,
    __bf16* __restrict__ d7, __bf16* __restrict__ d8,
    const float* __restrict__ cb1, const float* __restrict__ cb2,
    const float* __restrict__ cb3, float* __restrict__ yall) {
  __shared__ __align__(16) char smraw[49280];
  const int tid = threadIdx.x;

  if (blockIdx.x < 512) {
    __bf16* KsB = (__bf16*)smraw;              // 2 x 4096 bf16
    __bf16* VsB = KsB + 8192;                  // 2 x 4096 bf16
    float* T = (float*)(smraw + 32768);        // 4 x 1032 f32

    const int wave = tid >> 6, lane = tid & 63;
    const int swz = xcd_swz((int)blockIdx.x, 512);
    const int qb = swz % 16;
    const int bh = swz / 16;
    const int b = bh >> 3, h = bh & 7;
    const int q0 = qb * 64;
    const int cc = lane & 15, quad = lane >> 4;

    for (int j = tid; j < 1024; j += 256) {
      const int rv = rm[b * S_ + j];
      const float mk = amask[b * S_ + j] ? 1.f : 0.f;
#pragma unroll
      for (int ri = 0; ri < 4; ri++)
        T[ri * 1032 + j] = __expf(rbias[h * 16 + ri * 4 + rv]) * mk;
    }

    const int qrow = q0 + wave * 16;
    const int rmi = rm[b * S_ + qrow + cc];
    const float* Trow = T + rmi * 1032;

    const __bf16* Qr = QKV + (size_t)(b * S_ + qrow + cc) * QKVLD + h * 64;
    const bf16x8 qb0 = *(const bf16x8*)(Qr + quad * 8);
    const bf16x8 qb1 = *(const bf16x8*)(Qr + 32 + quad * 8);

    floatx4 of[4];
#pragma unroll
    for (int dc = 0; dc < 4; dc++) of[dc] = (floatx4){0.f, 0.f, 0.f, 0.f};
    float mold = -1e30f, l = 0.f;

    const int rsub = lane >> 3;
    const int sgch = ((lane & 7) ^ rsub) * 8;
    const __bf16* Kg = QKV + (size_t)(b * S_ + wave * 16 + rsub) * QKVLD + 512 + h * 64 + sgch;
    const __bf16* Vg = VT + (size_t)bh * 65536 + (size_t)(wave * 16 + rsub) * 1024 + sgch;

    auto stage = [&](int buf, int jt) {
      const int j0 = jt * 64;
#pragma unroll
      for (int i = 0; i < 2; i++) {
        g2l16(Kg + (size_t)(j0 + i * 8) * QKVLD, KsB + buf * 4096 + (wave * 16 + i * 8) * 64);
        g2l16(Vg + j0 + (size_t)(i * 8) * 1024, VsB + buf * 4096 + (wave * 16 + i * 8) * 64);
      }
    };

    stage(0, 0);
    int cur = 0;
    const int rk = cc & 7;

    for (int jt = 0; jt < 16; jt++) {
      const int j0 = jt * 64;
      __syncthreads();
      if (jt + 1 < 16) stage(cur ^ 1, jt + 1);
      const __bf16* Kb = KsB + cur * 4096;
      const __bf16* Vb = VsB + cur * 4096;

      floatx4 st[4];
      __builtin_amdgcn_s_setprio(1);
#pragma unroll
      for (int js = 0; js < 4; js++) {
        const bf16x8 ka0 = *(const bf16x8*)(Kb + (js * 16 + cc) * 64 + ((quad ^ rk) * 8));
        const bf16x8 ka1 = *(const bf16x8*)(Kb + (js * 16 + cc) * 64 + (((quad + 4) ^ rk) * 8));
        floatx4 s = (floatx4){0.f, 0.f, 0.f, 0.f};
        s = __builtin_amdgcn_mfma_f32_16x16x32_bf16(ka0, qb0, s, 0, 0, 0);
        s = __builtin_amdgcn_mfma_f32_16x16x32_bf16(ka1, qb1, s, 0, 0, 0);
        st[js] = s;
      }
      __builtin_amdgcn_s_setprio(0);

      float mxr = st[0][0];
#pragma unroll
      for (int js = 0; js < 4; js++)
#pragma unroll
        for (int i = 0; i < 4; i++) mxr = fmaxf(mxr, st[js][i]);
      mxr = fmaxf(mxr, __shfl_xor(mxr, 16));
      mxr = fmaxf(mxr, __shfl_xor(mxr, 32));
      const float mnew = fmaxf(mold, mxr * 0.125f);
      const float alpha = __expf(mold - mnew);
      mold = mnew;

      float rsum = 0.f;
      short4v pk[4];
#pragma unroll
      for (int js = 0; js < 4; js++) {
        const floatx4 Tv = *(const floatx4*)(Trow + j0 + js * 16 + quad * 4);
        union { __bf16 hh[4]; short4v s4v; } u;
#pragma unroll
        for (int i = 0; i < 4; i++) {
          const float p = __expf(fmaf(st[js][i], 0.125f, -mnew)) * Tv[i];
          rsum += p;
          u.hh[i] = (__bf16)p;
        }
        pk[js] = u.s4v;
      }
      rsum += __shfl_xor(rsum, 16);
      rsum += __shfl_xor(rsum, 32);
      l = l * alpha + rsum;

#pragma unroll
      for (int dc = 0; dc < 4; dc++)
#pragma unroll
        for (int i = 0; i < 4; i++) of[dc][i] *= alpha;

      __builtin_amdgcn_s_setprio(1);
#pragma unroll
      for (int dc = 0; dc < 4; dc++) {
#pragma unroll
        for (int js = 0; js < 4; js++) {
          union { bf16x4 v; short4v s4v; } va;
          va.v = *(const bf16x4*)(Vb + (dc * 16 + cc) * 64 +
                                  (((js * 2 + (quad >> 1)) ^ rk) * 8) + (quad & 1) * 4);
          of[dc] = __builtin_amdgcn_mfma_f32_16x16x16bf16_1k(va.s4v, pk[js], of[dc], 0, 0, 0);
        }
      }
      __builtin_amdgcn_s_setprio(0);
      cur ^= 1;
    }

    const float invl = 1.f / l;
    __bf16* po = O + (size_t)(b * S_ + qrow + cc) * D_ + h * 64;
#pragma unroll
    for (int dc = 0; dc < 4; dc++) {
      union { __bf16 hh[4]; unsigned long long u; } w;
#pragma unroll
      for (int i = 0; i < 4; i++) w.hh[i] = (__bf16)(of[dc][i] * invl);
      *(unsigned long long*)(po + dc * 16 + quad * 4) = w.u;
    }
    return;
  }

  int pb = blockIdx.x - 512;
  if (pb < 1408) {
    float* Ts = (float*)smraw;  // 4608 f32
    int id = pb;
    const float* cw;
    __bf16* wt;
    int lg, c, d0i, TD, L;
    if (id < 128) {
      cw = cw1; wt = wt4; lg = 2; c = id; d0i = 0; TD = 512; L = 2048;
    } else if (id < 384) {
      id -= 128;
      cw = cw2; wt = wt16; lg = 4; c = id >> 1; d0i = (id & 1) * 256; TD = 256; L = 4096;
    } else {
      id -= 384;
      cw = cw3; wt = wt64; lg = 6; c = id >> 3; d0i = (id & 7) * 64; TD = 64; L = 4096;
    }
    const int sc = 1 << lg;
    const int KD = 512 << lg;
    const float* src = cw + (size_t)c * KD + (size_t)d0i * sc;

    for (int f = tid * 4; f < L; f += 1024) {
      const float4 v = *(const float4*)(src + f);
      const float vv[4] = {v.x, v.y, v.z, v.w};
#pragma unroll
      for (int j = 0; j < 4; j++) {
        const int idx = f + j;
        const int dl = idx >> lg, k = idx & (sc - 1);
        Ts[dl * (sc + 1) + k] = vv[j];
      }
    }
    __syncthreads();

    for (int w = tid * 8; w < L; w += 2048) {
      const int kpos = w / TD;
      const int dl0 = w - kpos * TD;
      union { __bf16 hh[8]; bf16x8 v; } u;
#pragma unroll
      for (int j = 0; j < 8; j++)
        u.hh[j] = (__bf16)Ts[(dl0 + j) * (sc + 1) + kpos];
      *(bf16x8*)(wt + (size_t)c * KD + kpos * 512 + d0i + dl0) = u.v;
    }
    return;
  }

  const int qd = (pb - 1408) * 256 + tid;
  if (qd < 172032) {  // seed conv outputs with bias (cgemm3 atomically adds)
    float bb;
    if (qd < 131072) bb = cb1[qd & 127];
    else if (qd < 163840) bb = cb2[qd & 127];
    else bb = cb3[qd & 127];
    yall[qd] = bb;
  }
  const float* src;
  __bf16* dst;
  int base;
  if (qd < 65536) { src = s4; dst = d4; base = 0; }
  else if (qd < 131072) { src = s5; dst = d5; base = 65536; }
  else if (qd < 147456) { src = s6; dst = d6; base = 131072; }
  else if (qd < 409600) { src = s7; dst = d7; base = 147456; }
  else { src = s8; dst = d8; base = 409600; }
  const int local = qd - base;
  float4 v = *(const float4*)(src + (size_t)local * 4);
  union { __bf16 h[4]; unsigned long long u; } t;
  t.h[0] = (__bf16)v.x; t.h[1] = (__bf16)v.y;
  t.h[2] = (__bf16)v.z; t.h[3] = (__bf16)v.w;
  *(unsigned long long*)(dst + (size_t)local * 4) = t.u;
}

// ---------------------------------------------------------------------------
// R21: LN kernels take TWO GEMM partials + a bias vector (split-K sum + bias
// folded in): v = xa + h0 + h1 + bias[col].
// ---------------------------------------------------------------------------
__global__ __launch_bounds__(256) void add_ln_kernel(
    const float* __restrict__ xa, const float* __restrict__ h0,
    const float* __restrict__ h1, const float* __restrict__ bias,
    const float* __restrict__ g, const float* __restrict__ be,
    float* __restrict__ out, __bf16* __restrict__ outb) {
  const int row = (blockIdx.x * 256 + threadIdx.x) >> 6;
  const int lane = threadIdx.x & 63;
  const floatx4* pa = (const floatx4*)(xa + (size_t)row * D_);
  const floatx4* p0 = (const floatx4*)(h0 + (size_t)row * D_);
  const floatx4* p1 = (const floatx4*)(h1 + (size_t)row * D_);
  floatx4 v[2];
  float sum = 0.f;
#pragma unroll
  for (int i = 0; i < 2; i++) {
    const int dd = lane + 64 * i;
    v[i] = pa[dd] + p0[dd] + p1[dd] + ((const floatx4*)bias)[dd];
    sum += v[i][0] + v[i][1] + v[i][2] + v[i][3];
  }
#pragma unroll
  for (int off = 32; off; off >>= 1) sum += __shfl_xor(sum, off);
  const float mu = sum * (1.f / D_);
  float vs = 0.f;
#pragma unroll
  for (int i = 0; i < 2; i++)
#pragma unroll
    for (int j = 0; j < 4; j++) { float t = v[i][j] - mu; vs += t * t; }
#pragma unroll
  for (int off = 32; off; off >>= 1) vs += __shfl_xor(vs, off);
  const float inv = rsqrtf(vs * (1.f / D_) + 1e-5f);
  floatx4* po = (floatx4*)(out + (size_t)row * D_);
#pragma unroll
  for (int i = 0; i < 2; i++) {
    const int dd = lane + 64 * i;
    const floatx4 g4 = ((const floatx4*)g)[dd];
    const floatx4 b4 = ((const floatx4*)be)[dd];
    const floatx4 o = (v[i] - mu) * inv * g4 + b4;
    po[dd] = o;
    if (outb) {
      union { __bf16 hh[4]; unsigned long long u; } w;
#pragma unroll
      for (int j = 0; j < 4; j++) w.hh[j] = (__bf16)o[j];
      *(unsigned long long*)(outb + (size_t)row * D_ + dd * 4) = w.u;
    }
  }
}

__global__ __launch_bounds__(256) void ln_chain_kernel(
    const float* __restrict__ x1, const float* __restrict__ h0,
    const float* __restrict__ h1, const float* __restrict__ bias,
    const float* __restrict__ ltg, const float* __restrict__ ltb,
    const float* __restrict__ n2g, const float* __restrict__ n2b,
    float* __restrict__ out, __bf16* __restrict__ outb) {
  const int row = (blockIdx.x * 256 + threadIdx.x) >> 6;
  const int lane = threadIdx.x & 63;
  const floatx4* p1 = (const floatx4*)(x1 + (size_t)row * D_);
  const floatx4* pf0 = (const floatx4*)(h0 + (size_t)row * D_);
  const floatx4* pf1 = (const floatx4*)(h1 + (size_t)row * D_);
  floatx4 xv[2], u[2];
  float sum = 0.f;
#pragma unroll
  for (int i = 0; i < 2; i++) {
    const int dd = lane + 64 * i;
    xv[i] = p1[dd];
    u[i] = xv[i] + pf0[dd] + pf1[dd] + ((const floatx4*)bias)[dd];
    sum += u[i][0] + u[i][1] + u[i][2] + u[i][3];
  }
#pragma unroll
  for (int off = 32; off; off >>= 1) sum += __shfl_xor(sum, off);
  float mu = sum * (1.f / D_);
  float vs = 0.f;
#pragma unroll
  for (int i = 0; i < 2; i++)
#pragma unroll
    for (int j = 0; j < 4; j++) { float t = u[i][j] - mu; vs += t * t; }
#pragma unroll
  for (int off = 32; off; off >>= 1) vs += __shfl_xor(vs, off);
  float inv = rsqrtf(vs * (1.f / D_) + 1e-5f);
  float sum2 = 0.f;
#pragma unroll
  for (int i = 0; i < 2; i++) {
    const int dd = lane + 64 * i;
    const floatx4 g4 = ((const floatx4*)ltg)[dd];
    const floatx4 b4 = ((const floatx4*)ltb)[dd];
    u[i] = xv[i] + ((u[i] - mu) * inv * g4 + b4);
    sum2 += u[i][0] + u[i][1] + u[i][2] + u[i][3];
  }
#pragma unroll
  for (int off = 32; off; off >>= 1) sum2 += __shfl_xor(sum2, off);
  float mu2 = sum2 * (1.f / D_);
  float vs2 = 0.f;
#pragma unroll
  for (int i = 0; i < 2; i++)
#pragma unroll
    for (int j = 0; j < 4; j++) { float t = u[i][j] - mu2; vs2 += t * t; }
#pragma unroll
  for (int off = 32; off; off >>= 1) vs2 += __shfl_xor(vs2, off);
  float inv2 = rsqrtf(vs2 * (1.f / D_) + 1e-5f);
  floatx4* po = (floatx4*)(out + (size_t)row * D_);
#pragma unroll
  for (int i = 0; i < 2; i++) {
    const int dd = lane + 64 * i;
    const floatx4 g4 = ((const floatx4*)n2g)[dd];
    const floatx4 b4 = ((const floatx4*)n2b)[dd];
    const floatx4 o = (u[i] - mu2) * inv2 * g4 + b4;
    po[dd] = o;
    union { __bf16 hh[4]; unsigned long long u8; } w;
#pragma unroll
    for (int j = 0; j < 4; j++) w.hh[j] = (__bf16)o[j];
    *(unsigned long long*)(outb + (size_t)row * D_ + dd * 4) = w.u8;
  }
}

// ---------------------------------------------------------------------------
// R20: interp vectorized x4 along channels.
// ---------------------------------------------------------------------------
__global__ void interp_kernel(const float* __restrict__ y1, const float* __restrict__ y2,
                              const float* __restrict__ y3, __bf16* __restrict__ ms) {
  int idx = blockIdx.x * 256 + threadIdx.x;
  if (idx >= B_ * S_ * 3 * C_ / 4) return;
  const int c3_4 = idx % 96;
  const int rest = idx / 96;
  const int s = rest & 1023, b = rest >> 10;
  const int i = c3_4 >> 5;
  const int c = (c3_4 & 31) * 4;
  const int Lin = (i == 0) ? 256 : (i == 1) ? 64 : 16;
  const float* y = (i == 0) ? y1 : (i == 1) ? y2 : y3;
  float pos = (s + 0.5f) * ((float)Lin / S_) - 0.5f;
  pos = fminf(fmaxf(pos, 0.f), (float)(Lin - 1));
  const int lo = (int)floorf(pos);
  const int hi = min(lo + 1, Lin - 1);
  const float w = pos - (float)lo;
  const float* ybase = y + ((size_t)(b * Lin + lo)) * 128 + c;
  const floatx4 vlo = *(const floatx4*)ybase;
  const floatx4 vhi = *(const floatx4*)(ybase + (size_t)(hi - lo) * 128);
  const floatx4 o = vlo * (1.f - w) + vhi * w;
  union { __bf16 hh[4]; unsigned long long u; } t;
#pragma unroll
  for (int j = 0; j < 4; j++) t.hh[j] = (__bf16)o[j];
  *(unsigned long long*)(ms + ((size_t)b * S_ + s) * D_ + C_ + i * 128 + c) = t.u;
}

// ---------------------------------------------------------------------------
extern "C" void kernel_launch(void* const* d_in, const int* in_sizes, int n_in,
                              void* d_out, int out_size, void* d_ws, size_t ws_size,
                              hipStream_t stream) {
  const float* x   = (const float*)d_in[0];
  const int* rm    = (const int*)d_in[1];
  const int* am    = (const int*)d_in[2];
  const float* wq  = (const float*)d_in[3];
  const float* bq  = (const float*)d_in[4];
  const float* wk  = (const float*)d_in[5];
  const float* bk  = (const float*)d_in[6];
  const float* wv  = (const float*)d_in[7];
  const float* bv  = (const float*)d_in[8];
  const float* wo  = (const float*)d_in[9];
  const float* bo  = (const float*)d_in[10];
  const float* rbias = (const float*)d_in[11];
  const float* cw0 = (const float*)d_in[12];
  const float* cb0 = (const float*)d_in[13];
  const float* cw1 = (const float*)d_in[14];
  const float* cb1 = (const float*)d_in[15];
  const float* cw2 = (const float*)d_in[16];
  const float* cb2 = (const float*)d_in[17];
  const float* cw3 = (const float*)d_in[18];
  const float* cb3 = (const float*)d_in[19];
  const float* fw  = (const float*)d_in[20];
  const float* fb  = (const float*)d_in[21];
  const float* ltg = (const float*)d_in[22];
  const float* ltb = (const float*)d_in[23];
  const float* n1g = (const float*)d_in[24];
  const float* n1b = (const float*)d_in[25];
  const float* n2g = (const float*)d_in[26];
  const float* n2b = (const float*)d_in[27];
  const float* fw1 = (const float*)d_in[28];
  const float* fb1 = (const float*)d_in[29];
  const float* fw2 = (const float*)d_in[30];
  const float* fb2 = (const float*)d_in[31];
  const float* n3g = (const float*)d_in[32];
  const float* n3b = (const float*)d_in[33];

  float* ws = (float*)d_ws;
  __bf16* wqkvb = (__bf16*)(ws + 0);         // 768K elems
  __bf16* wob   = (__bf16*)(ws + 393216);    // 256K
  __bf16* fwb   = (__bf16*)(ws + 524288);    // 256K
  __bf16* cw0b  = (__bf16*)(ws + 655360);    // 64K
  __bf16* fw1b  = (__bf16*)(ws + 688128);    // 1M
  __bf16* fw2b  = (__bf16*)(ws + 1212416);   // 1M
  __bf16* xb    = (__bf16*)(ws + 1835008);   // 2M elems [dead after qkv gemm]
  __bf16* qkv   = (__bf16*)(ws + 2883584);   // 6M elems [dead after attn]
  __bf16* attnb = (__bf16*)(ws + 6029312);   // 2M elems [dead after wo gemm]
  float*  x1    = ws + 7077888;              // 2M f [dead after ln_chain]
  __bf16* x1b   = (__bf16*)(ws + 9175040);   // 2M elems
  float*  scr   = ws + 10223616;             // 2M f
  float*  x2    = ws + 12320768;             // 2M f
  __bf16* x2b   = (__bf16*)(ws + 14417920);  // 2M elems
  __bf16* msb   = (__bf16*)(ws + 15466496);  // 2M elems
  float*  y1    = ws + 16515072;             // 131072 f (t-major 1024x128)
  float*  y2    = ws + 16646144;             // 32768 f
  float*  y3    = ws + 16678912;             // 8192 f
  float*  bqkv  = ws + 16687104;             // 1536 f
  __bf16* wt4b  = (__bf16*)(ws + 16689152);  // 262144 elems
  __bf16* wt16b = (__bf16*)(ws + 16820224);  // 1048576 elems
  __bf16* wt64b = (__bf16*)(ws + 17344512);  // 4194304 elems
  // overlays (lifetime-disjoint):
  __bf16* VT    = (__bf16*)(ws + 10223616);  // 2M elems over scr (attn phase)
  __bf16* ffh   = (__bf16*)(ws + 2883584);   // 8M elems over qkv+attnb (FFN phase)
  float*  h1a   = ws + 2883584;              // 2M f over qkv (wo/fuse split-K half-1)

  dim3 blk(256);

  // prepA: only the qkv-critical casts (x, wq/wk/wv, bqkv)
  prepA<<<2816, blk, 0, stream>>>(
      x, wq, wk, wv,
      xb, wqkvb, wqkvb + 262144, wqkvb + 524288,
      bq, bk, bv, bqkv);

  // qkv GEMM: 64x128 tiles, 768 blocks = exactly 3 blocks/CU x 256 CUs
  mgemm_qkv<<<768, blk, 0, stream>>>(xb, wqkvb, bqkv, qkv, VT);

  // fattn (512 blocks) + the rest of prep (4032 blocks) in ONE dispatch
  fattnP<<<4544, blk, 0, stream>>>(
      qkv, VT, rbias, rm, am, attnb,
      cw1, cw2, cw3, wt4b, wt16b, wt64b,
      wo, fw, cw0, fw1, fw2,
      wob, fwb, cw0b, fw1b, fw2b,
      cb1, cb2, cb3, y1);

  // wo projection: split-K (2x256) -> scr + h1a (qkv region is dead now)
  mgemm64s<<<dim3(8, 128), blk, 0, stream>>>(attnb, wob, scr, h1a, 512, 256);
  add_ln_kernel<<<1024, blk, 0, stream>>>(x, scr, h1a, bo, n1g, n1b, x1, x1b);

  cgemm3<<<256, blk, 0, stream>>>(x1b, wt4b, wt16b, wt64b, cw0b, cb0, y1, y2, y3, msb);
  interp_kernel<<<1536, blk, 0, stream>>>(y1, y2, y3, msb);

  // fuse GEMM: split-K (2x256) -> scr + h1a
  mgemm64s<<<dim3(8, 128), blk, 0, stream>>>(msb, fwb, scr, h1a, 512, 256);
  ln_chain_kernel<<<1024, blk, 0, stream>>>(x1, scr, h1a, fb, ltg, ltb, n2g, n2b, x2, x2b);

  mgemm<true, true, false><<<dim3(16, 32), blk, 0, stream>>>(
      x2b, fw1b, fb1, ffh, 4096, 2048, 512, 2048, nullptr);
  // ffn2: split-K (2x1024; scr + x1 are dead f32 buffers; x1 starts exactly
  // at ffh's end so no overlap with the live ffh input)
  mgemm64s<<<dim3(8, 128), blk, 0, stream>>>(ffh, fw2b, scr, x1, 2048, 1024);
  add_ln_kernel<<<1024, blk, 0, stream>>>(x2, scr, x1, fb2, n3g, n3b, (float*)d_out, nullptr);
}